// Round 3
// baseline (3554.749 us; speedup 1.0000x reference)
//
#include <hip/hip_runtime.h>
#include <hip/hip_bf16.h>
#include <cstdint>

#define LEAKV 0.2f
static const int Bb = 4, Nn = 4096, Mm = 16384, Kk = 20, Ss = 8;

__device__ __forceinline__ float lrelu_f(float v){ return v > 0.f ? v : LEAKV*v; }

// ---------- dtype detector: read as bf16, count wild values ----------
__global__ void detect_kernel(const void* __restrict__ xyz, int n, int* __restrict__ flag){
  __shared__ int cnt;
  if (threadIdx.x == 0) cnt = 0;
  __syncthreads();
  const __hip_bfloat16* p = (const __hip_bfloat16*)xyz;
  int local = 0;
  for (int i = threadIdx.x; i < n; i += 256){
    float v = __bfloat162float(p[i]);
    if (!(fabsf(v) < 1000.f)) local++;   // catches NaN/Inf/huge
  }
  atomicAdd(&cnt, local);
  __syncthreads();
  if (threadIdx.x == 0) *flag = (cnt < n/16) ? 1 : 0;   // 1 = bf16, 0 = fp32
}

// ---------- flag-gated input load -> fp32 ----------
__global__ void load_input_kernel(const void* __restrict__ src, const int* __restrict__ flag,
                                  float* __restrict__ out, int n){
  int t = blockIdx.x*256 + threadIdx.x;
  if (t >= n) return;
  if (*flag) out[t] = __bfloat162float(((const __hip_bfloat16*)src)[t]);
  else       out[t] = ((const float*)src)[t];
}

// ---------- flag-gated output store ----------
__global__ void store_out_kernel(const float* __restrict__ src, const int* __restrict__ flag,
                                 void* __restrict__ dst, int n){
  int t = blockIdx.x*256 + threadIdx.x;
  if (t >= n) return;
  float v = src[t];
  if (*flag) ((__hip_bfloat16*)dst)[t] = __float2bfloat16(v);
  else       ((float*)dst)[t] = v;
}

// ---------- squared norms ----------
__global__ void norms_kernel(const float* __restrict__ x, int ld, int C, int total, float* __restrict__ out){
  int t = blockIdx.x*256 + threadIdx.x;
  if (t >= total) return;
  const float* r = x + (size_t)t*ld;
  float s = 0.f;
  for (int c = 0; c < C; ++c){ float v = r[c]; s += v*v; }
  out[t] = s;
}

// ---------- KNN partial top-20 over a candidate split ----------
template<int C>
__global__ __launch_bounds__(256) void knn_part_kernel(
    const float* __restrict__ x, int ld, const float* __restrict__ n2,
    float* __restrict__ outd, int* __restrict__ outi)
{
  const int tid = threadIdx.x;
  const int b = blockIdx.z, s = blockIdx.y;
  const int q = blockIdx.x*256 + tid;
  const int bN = b*Nn;
  const int TC = 64;
  const int CS = Nn / Ss;
  __shared__ __align__(16) float sf[TC*C];
  __shared__ float sn[TC];
  float qv[C];
  {
    const float* qr = x + (size_t)(bN + q)*ld;
    #pragma unroll
    for (int c = 0; c < C; ++c) qv[c] = qr[c];
  }
  float bd[20]; int bi[20];
  #pragma unroll
  for (int l = 0; l < 20; ++l){ bd[l] = 1e30f; bi[l] = 0; }
  float worst = 1e30f; int wp = 0;
  for (int t0 = 0; t0 < CS; t0 += TC){
    const int j0 = s*CS + t0;
    __syncthreads();
    for (int e = tid; e < TC*C; e += 256){
      int j = e / C, c = e - j*C;
      sf[e] = x[(size_t)(bN + j0 + j)*ld + c];
    }
    if (tid < TC) sn[tid] = n2[bN + j0 + tid];
    __syncthreads();
    for (int jj = 0; jj < TC; ++jj){
      float dot = 0.f;
      if (C % 4 == 0){
        const float4* p = reinterpret_cast<const float4*>(&sf[jj*C]);
        #pragma unroll
        for (int c4 = 0; c4 < C/4; ++c4){
          float4 v = p[c4];
          dot += qv[c4*4+0]*v.x + qv[c4*4+1]*v.y + qv[c4*4+2]*v.z + qv[c4*4+3]*v.w;
        }
      } else {
        #pragma unroll
        for (int c = 0; c < C; ++c) dot += qv[c]*sf[jj*C+c];
      }
      float d = sn[jj] - 2.f*dot;
      if (d < worst){
        int j = j0 + jj;
        #pragma unroll
        for (int l = 0; l < 20; ++l) if (l == wp){ bd[l] = d; bi[l] = j; }
        worst = bd[0]; wp = 0;
        #pragma unroll
        for (int l = 1; l < 20; ++l) if (bd[l] > worst){ worst = bd[l]; wp = l; }
      }
    }
  }
  size_t base = ((size_t)(bN + q)*Ss + s)*20;
  #pragma unroll
  for (int l = 0; l < 20; ++l){ outd[base+l] = bd[l]; outi[base+l] = bi[l]; }
}

// ---------- merge S partial lists -> final 20 ----------
__global__ void knn_merge_kernel(const float* __restrict__ ind, const int* __restrict__ ini,
                                 int total, int* __restrict__ idx)
{
  int t = blockIdx.x*256 + threadIdx.x;
  if (t >= total) return;
  float bd[20]; int bi[20];
  #pragma unroll
  for (int l=0;l<20;++l){ bd[l]=1e30f; bi[l]=0; }
  float worst = 1e30f; int wp = 0;
  size_t base = (size_t)t*Ss*20;
  for (int e = 0; e < Ss*20; ++e){
    float d = ind[base+e];
    if (d < worst){
      int j = ini[base+e];
      #pragma unroll
      for (int l=0;l<20;++l) if (l==wp){ bd[l]=d; bi[l]=j; }
      worst = bd[0]; wp = 0;
      #pragma unroll
      for (int l=1;l<20;++l) if (bd[l]>worst){ worst=bd[l]; wp=l; }
    }
  }
  #pragma unroll
  for (int l=0;l<20;++l) idx[(size_t)t*20+l] = bi[l];
}

// ---------- prepare edgeconv weights (fp32 in): wcat = [w_d ; w_x - w_d] ----------
__global__ void prep_w_kernel(const float* __restrict__ w, int C, int o0, int Osub,
                              float* __restrict__ wcat){
  int t = blockIdx.x*256 + threadIdx.x;
  if (t >= Osub*C) return;
  int o = t / C, c = t - o*C;
  int og = o0 + o;
  float wd = w[og*2*C + c];
  float wx = w[og*2*C + C + c];
  wcat[o*C + c] = wd;
  wcat[(Osub+o)*C + c] = wx - wd;
}

// ---------- gather-max epilogue of edgeconv ----------
__global__ void gathermax_kernel(const float* __restrict__ tb, const int* __restrict__ idx,
                                 const float* __restrict__ sv, const float* __restrict__ bv,
                                 int O, float* __restrict__ out, int ldo)
{
  int t = blockIdx.x*256 + threadIdx.x;
  int o = t % O;
  int m = t / O;           // b*N + i
  int b = m / Nn;
  const int twoO = 2*O;
  const int* ip = idx + (size_t)m*Kk;
  float mx = -1e30f;
  for (int j = 0; j < Kk; ++j){
    int jj = ip[j] & (Nn-1);
    mx = fmaxf(mx, tb[(size_t)(b*Nn + jj)*twoO + o]);
  }
  float basev = tb[(size_t)m*twoO + O + o];
  float y = (mx + basev) * sv[o] + bv[o];
  out[(size_t)m*ldo + o] = lrelu_f(y);
}

// ---------- ordered-uint float max keys ----------
__device__ __forceinline__ unsigned fkey(float f){
  unsigned u = __float_as_uint(f);
  return (u & 0x80000000u) ? ~u : (u | 0x80000000u);
}
__device__ __forceinline__ float funkey(unsigned k){
  if (k == 0u) return -1e30f;
  unsigned u = (k & 0x80000000u) ? (k ^ 0x80000000u) : ~k;
  return __uint_as_float(u);
}

// ---------- generic fp32 GEMM: C[M,O] = A[M,K] @ W[O,K]^T (+epilogue / pool) ----------
__global__ __launch_bounds__(256) void gemm_kernel(
    const float* __restrict__ A, int lda,
    const float* __restrict__ W, int ldw,
    float* __restrict__ Cf, int ldc,
    int K, int O,
    const float* __restrict__ scale, const float* __restrict__ bias,
    const float* __restrict__ addvec, int lrelu_flag,
    unsigned* __restrict__ pool)
{
  const int tid = threadIdx.x;
  const int tx = tid & 15, ty = tid >> 4;
  const int m0 = blockIdx.y * 64;
  const int o0 = blockIdx.x * 64;
  __shared__ __align__(16) float As[16*68];
  __shared__ __align__(16) float Ws[16*68];
  float acc[4][4] = {};
  for (int k0 = 0; k0 < K; k0 += 16){
    __syncthreads();
    #pragma unroll
    for (int r = 0; r < 4; ++r){
      int e = tid + r*256;
      int k = e & 15, mi = e >> 4;
      int kk = k0 + k;
      float v = 0.f, wv = 0.f;
      if (kk < K) v = A[(size_t)(m0+mi)*lda + kk];
      int oo = o0 + mi;
      if (kk < K && oo < O) wv = W[(size_t)oo*ldw + kk];
      As[k*68 + mi] = v;
      Ws[k*68 + mi] = wv;
    }
    __syncthreads();
    #pragma unroll
    for (int kk = 0; kk < 16; ++kk){
      float4 av = *reinterpret_cast<const float4*>(&As[kk*68 + ty*4]);
      float4 wv = *reinterpret_cast<const float4*>(&Ws[kk*68 + tx*4]);
      float a4[4] = {av.x, av.y, av.z, av.w};
      float w4[4] = {wv.x, wv.y, wv.z, wv.w};
      #pragma unroll
      for (int i = 0; i < 4; ++i)
        #pragma unroll
        for (int j = 0; j < 4; ++j)
          acc[i][j] += a4[i]*w4[j];
    }
  }
  const int b = m0 / Nn;
  if (pool){
    float cm[4];
    #pragma unroll
    for (int j = 0; j < 4; ++j){
      int o = o0 + tx*4 + j;
      float m = -1e30f;
      #pragma unroll
      for (int i = 0; i < 4; ++i){
        float y = acc[i][j];
        if (addvec) y += addvec[b*O + o];
        y = y*scale[o] + bias[o];
        y = lrelu_f(y);
        m = fmaxf(m, y);
      }
      cm[j] = m;
    }
    __syncthreads();
    #pragma unroll
    for (int j = 0; j < 4; ++j) As[ty*68 + tx*4 + j] = cm[j];
    __syncthreads();
    if (tid < 64){
      float m = -1e30f;
      #pragma unroll
      for (int r = 0; r < 16; ++r) m = fmaxf(m, As[r*68 + tid]);
      atomicMax(&pool[b*O + o0 + tid], fkey(m));
    }
    return;
  }
  #pragma unroll
  for (int i = 0; i < 4; ++i){
    int m = m0 + ty*4 + i;
    #pragma unroll
    for (int j = 0; j < 4; ++j){
      int o = o0 + tx*4 + j;
      if (o >= O) continue;
      float y = acc[i][j];
      if (addvec) y += addvec[b*O + o];
      if (scale)  y = y*scale[o] + bias[o];
      else if (bias) y += bias[o];
      if (lrelu_flag) y = lrelu_f(y);
      Cf[(size_t)m*ldc + o] = y;
    }
  }
}

__global__ void init_u32_kernel(unsigned* __restrict__ p, int n){
  int t = blockIdx.x*256 + threadIdx.x;
  if (t < n) p[t] = 0u;
}
// gvec[b,o2] = sum_c wh1[o2, 512+c] * glob[b,c]
__global__ void gvec_kernel(const float* __restrict__ wh1, int ldw, const unsigned* __restrict__ glob,
                            int Oe, int O2, float* __restrict__ gv){
  int o2 = threadIdx.x; int b = blockIdx.x;
  const float* wr = wh1 + (size_t)o2*ldw + 512;
  float s = 0.f;
  for (int c = 0; c < Oe; ++c) s += wr[c] * funkey(glob[b*Oe + c]);
  gv[b*O2 + o2] = s;
}

extern "C" void kernel_launch(void* const* d_in, const int* in_sizes, int n_in,
                              void* d_out, int out_size, void* d_ws, size_t ws_size,
                              hipStream_t stream) {
  (void)in_sizes; (void)n_in; (void)out_size; (void)ws_size;

  float* ws = (float*)d_ws;
  size_t off = 0;
  auto alloc = [&](size_t n){ float* p = ws + off; off += n; return p; };
  int*   dflag = (int*)alloc(16);
  float* xyzf = alloc((size_t)Mm*3);
  float* w1f  = alloc(64*6);
  float* w2f  = alloc(64*128);
  float* w3f  = alloc(128*256);
  float* w4f  = alloc(256*512);
  float* wff  = alloc(512*512);
  float* wef  = alloc(1024*512);
  float* wh1f = alloc(256*1536);
  float* wh2f = alloc(256*256);
  float* wh3f = alloc(50*256);
  float* wcat = alloc(512*128);
  float* nrm  = alloc(Mm);
  int*   idx  = (int*)alloc((size_t)Mm*Kk);
  unsigned* glob = (unsigned*)alloc(4096);
  float* gv   = alloc(1024);
  float* sfv = alloc(512);  float* bfv = alloc(512);
  float* sev = alloc(1024); float* bev = alloc(1024);
  float* sh1v = alloc(256); float* bh1v = alloc(256);
  float* sh2v = alloc(256); float* bh2v = alloc(256);
  float* bh3v = alloc(64);
  float* s1v = alloc(64);  float* b1v = alloc(64);
  float* s2v = alloc(64);  float* b2v = alloc(64);
  float* s3v = alloc(128); float* b3v = alloc(128);
  float* s4v = alloc(256); float* b4v = alloc(256);
  // big regions
  const size_t SL = (size_t)Mm*512;        // 8.39M floats
  float* xcat = ws + 2000000;              // [M,512]
  float* regC = ws + 10400000;             // 32MB multipurpose
  float* dpart = regC;
  int*   ipart = (int*)(regC + (size_t)Mm*Ss*20);
  float* tb    = regC;                     // [M, <=256]
  float* xloc  = regC;                     // [M,512]
  float* logitsF = regC;                   // [M,50] (xloc dead by then)
  float* h1 = xcat;                        // [M,256]
  float* h2 = xcat + (size_t)Mm*256;       // [M,256]

  // ---- dtype detect, then flag-gated conversions ----
  detect_kernel<<<1, 256, 0, stream>>>(d_in[0], Mm*3, dflag);
  auto cvt = [&](int i, float* dst, int n){
    load_input_kernel<<<(n+255)/256, 256, 0, stream>>>(d_in[i], dflag, dst, n);
  };
  cvt(0, xyzf, Mm*3);
  cvt(2, w1f, 64*6);    cvt(3, s1v, 64);   cvt(4, b1v, 64);
  cvt(5, w2f, 64*128);  cvt(6, s2v, 64);   cvt(7, b2v, 64);
  cvt(8, w3f, 128*256); cvt(9, s3v, 128);  cvt(10, b3v, 128);
  cvt(11, w4f, 256*512);cvt(12, s4v, 256); cvt(13, b4v, 256);
  cvt(14, wff, 512*512);  cvt(15, sfv, 512);  cvt(16, bfv, 512);
  cvt(17, wef, 1024*512); cvt(18, sev, 1024); cvt(19, bev, 1024);
  cvt(20, wh1f, 256*1536);cvt(21, sh1v, 256); cvt(22, bh1v, 256);
  cvt(23, wh2f, 256*256); cvt(24, sh2v, 256); cvt(25, bh2v, 256);
  cvt(26, wh3f, 50*256);  cvt(27, bh3v, 50);
  init_u32_kernel<<<16, 256, 0, stream>>>(glob, 4096);

  auto gemm = [&](const float* A, int lda, const float* W, int ldw,
                  float* Cf, int ldc, int K, int O,
                  const float* sc, const float* bi, const float* av, int lr,
                  unsigned* pool){
    dim3 g((O+63)/64, Mm/64);
    gemm_kernel<<<g, 256, 0, stream>>>(A, lda, W, ldw, Cf, ldc, K, O, sc, bi, av, lr, pool);
  };

  auto edgeconv = [&](const float* xin, int ld, int C, int O,
                      const float* w, const float* sv, const float* bv,
                      float* xout, int ldo){
    norms_kernel<<<Mm/256, 256, 0, stream>>>(xin, ld, C, Mm, nrm);
    dim3 g(Nn/256, Ss, Bb);
    if (C == 3)       knn_part_kernel<3><<<g, 256, 0, stream>>>(xin, ld, nrm, dpart, ipart);
    else if (C == 64) knn_part_kernel<64><<<g, 256, 0, stream>>>(xin, ld, nrm, dpart, ipart);
    else              knn_part_kernel<128><<<g, 256, 0, stream>>>(xin, ld, nrm, dpart, ipart);
    knn_merge_kernel<<<Mm/256, 256, 0, stream>>>(dpart, ipart, Mm, idx);
    int chunk = (O > 128) ? 128 : O;
    for (int o0 = 0; o0 < O; o0 += chunk){
      int Osub = chunk;
      prep_w_kernel<<<(Osub*C+255)/256, 256, 0, stream>>>(w, C, o0, Osub, wcat);
      gemm(xin, ld, wcat, C, tb, 2*Osub, C, 2*Osub, nullptr, nullptr, nullptr, 0, nullptr);
      gathermax_kernel<<<((size_t)Mm*Osub)/256, 256, 0, stream>>>(
          tb, idx, sv + o0, bv + o0, Osub, xout + o0, ldo);
    }
  };

  edgeconv(xyzf, 3, 3, 64,            w1f, s1v, b1v, xcat + 0,   512);
  edgeconv(xcat + 0,   512, 64, 64,   w2f, s2v, b2v, xcat + 64,  512);
  edgeconv(xcat + 64,  512, 64, 128,  w3f, s3v, b3v, xcat + 128, 512);
  edgeconv(xcat + 128, 512, 128, 256, w4f, s4v, b4v, xcat + 256, 512);

  // x_local = lrelu((x_cat @ wf^T)*sf + bf)
  gemm(xcat, 512, wff, 512, xloc, 512, 512, 512, sfv, bfv, nullptr, 1, nullptr);
  // x_emb GEMM fused with global max pool -> glob
  gemm(xloc, 512, wef, 512, nullptr, 0, 512, 1024, sev, bev, nullptr, 1, glob);
  gvec_kernel<<<Bb, 256, 0, stream>>>(wh1f, 1536, glob, 1024, 256, gv);
  // h1 = lrelu((x_local @ wh1[:, :512]^T + gvec)*sh1 + bh1)
  gemm(xloc, 512, wh1f, 1536, h1, 256, 512, 256, sh1v, bh1v, gv, 1, nullptr);
  // h2
  gemm(h1, 256, wh2f, 256, h2, 256, 256, 256, sh2v, bh2v, nullptr, 1, nullptr);
  // logits (fp32 scratch), then flag-gated store to d_out
  gemm(h2, 256, wh3f, 256, logitsF, 50, 256, 50, nullptr, bh3v, nullptr, 0, nullptr);
  store_out_kernel<<<((size_t)Mm*50 + 255)/256, 256, 0, stream>>>(logitsF, dflag, d_out, Mm*50);
}